// Round 3
// baseline (869.305 us; speedup 1.0000x reference)
//
#include <hip/hip_runtime.h>
#include <hip/hip_bf16.h>
#include <stdint.h>

// LittleBitLinear: y = [(x*v2) @ sign(V)^T * (v1*u2)] @ sign(U)^T * u1  (x2 branches) + bias
// All inputs are FLOAT32 (per reference setup_inputs); output is FLOAT32.
// Strategy: fold all scales into binarized weights -> two bf16 MFMA GEMMs.
//   Xb  [8192][4096]  bf16 copy of x
//   Wb1 [2048][4096]  bf16 (B^T layout), rows 0..1023 branch1, 1024..2047 branch2
//   H   [8192][2048]  bf16 = Xb @ Wb1^T
//   Wb2 [4096][2048]  bf16 (B^T layout), K-concat of both branches, scaled by u1
//   Y   [8192][4096]  fp32 = H @ Wb2^T + bias

typedef __bf16 bf16x8 __attribute__((ext_vector_type(8)));
typedef float f32x4 __attribute__((ext_vector_type(4)));

__device__ __forceinline__ float sgn(float v) {
  return (v > 0.f) ? 1.f : ((v < 0.f) ? -1.f : 0.f);
}

__device__ __forceinline__ void store_out(float* p, float v) { *p = v; }
__device__ __forceinline__ void store_out(__hip_bfloat16* p, float v) { *p = __float2bfloat16(v); }

// fp32 -> bf16, 8 elements/thread, vectorized
__global__ __launch_bounds__(256) void convert_x(const float* __restrict__ x,
                                                 __hip_bfloat16* __restrict__ xb,
                                                 int n) {
  int i = (blockIdx.x * 256 + threadIdx.x) * 8;
  if (i >= n) return;
  const float4* p0 = (const float4*)(x + i);
  float4 a = p0[0], b = p0[1];
  __hip_bfloat16 o[8] = {
      __float2bfloat16(a.x), __float2bfloat16(a.y), __float2bfloat16(a.z), __float2bfloat16(a.w),
      __float2bfloat16(b.x), __float2bfloat16(b.y), __float2bfloat16(b.z), __float2bfloat16(b.w)};
  *(uint4*)(xb + i) = *(const uint4*)o;
}

// Wb1[s][k] = sign(V[s][k]) * v2[k] * v1[s] * u2[s]   (s<1024: branch1, else branch2)
__global__ __launch_bounds__(256) void prep_w1(
    const float* __restrict__ V, const float* __restrict__ v2,
    const float* __restrict__ v1, const float* __restrict__ u2,
    const float* __restrict__ V_R, const float* __restrict__ v2_R,
    const float* __restrict__ v1_R, const float* __restrict__ u2_R,
    __hip_bfloat16* __restrict__ W) {
  int g = blockIdx.x * 256 + threadIdx.x;  // one thread -> 8 consecutive k
  int k = (g & 511) * 8;                   // 4096 / 8 = 512 groups per row
  int s = g >> 9;                          // 0..2047
  const float *Vp, *v2p;
  float rs;
  if (s < 1024) {
    Vp = V + s * 4096 + k; v2p = v2 + k; rs = v1[s] * u2[s];
  } else {
    int ss = s - 1024;
    Vp = V_R + ss * 4096 + k; v2p = v2_R + k; rs = v1_R[ss] * u2_R[ss];
  }
  __hip_bfloat16 o[8];
#pragma unroll
  for (int e = 0; e < 8; ++e)
    o[e] = __float2bfloat16(sgn(Vp[e]) * v2p[e] * rs);
  *(uint4*)(W + s * 4096 + k) = *(const uint4*)o;
}

// Wb2[j][s] = sign(U[j][s]) * u1[j]  (s<1024 branch1, else branch2)
__global__ __launch_bounds__(256) void prep_w2(
    const float* __restrict__ U, const float* __restrict__ u1,
    const float* __restrict__ U_R, const float* __restrict__ u1_R,
    __hip_bfloat16* __restrict__ W) {
  int g = blockIdx.x * 256 + threadIdx.x;  // one thread -> 8 consecutive s
  int s = (g & 255) * 8;                   // 2048 / 8 = 256 groups per row
  int j = g >> 8;                          // 0..4095
  const float* Up;
  float sc;
  if (s < 1024) { Up = U + j * 1024 + s;            sc = u1[j]; }
  else          { Up = U_R + j * 1024 + (s - 1024); sc = u1_R[j]; }
  __hip_bfloat16 o[8];
#pragma unroll
  for (int e = 0; e < 8; ++e)
    o[e] = __float2bfloat16(sgn(Up[e]) * sc);
  *(uint4*)(W + j * 2048 + s) = *(const uint4*)o;
}

// C[M][N] = A[M][K] @ Bt[N][K]^T (+bias), bf16 in, fp32 acc.
// 128x128 block tile, 4 waves (2x2), each wave 64x64 = 4x4 MFMA 16x16x32 tiles.
// BK=32. LDS chunk-major: slot s in [0,512): chunk=s>>7 (k-octet), row=s&127;
// cell=16B (8 bf16). Fragment reads are ds_read_b128, conflict-free.
template <typename OutT>
__global__ __launch_bounds__(256) void gemm_bt(
    const __hip_bfloat16* __restrict__ A,
    const __hip_bfloat16* __restrict__ Bt,
    OutT* __restrict__ C,
    const float* __restrict__ bias,
    int K, int N) {
  __shared__ char smem[16384];  // A tile [0,8192), B tile [8192,16384)
  const int t = threadIdx.x;
  const int lane = t & 63;
  const int w = t >> 6;
  const int wm = (w >> 1) << 6;   // wave M offset in tile
  const int wn = (w & 1) << 6;    // wave N offset in tile
  const int bm = blockIdx.y << 7;
  const int bn = blockIdx.x << 7;
  const int quad = lane >> 4;
  const int l16 = lane & 15;

  f32x4 acc[4][4] = {};

  // staging: 512 slots per tile, 256 threads -> 2 slots each per tile
  const int s0 = t, s1 = t + 256;
  const int ch0 = s0 >> 7, r0 = s0 & 127;
  const int ch1 = s1 >> 7, r1 = s1 & 127;
  const uint4* gA = (const uint4*)A;
  const uint4* gB = (const uint4*)Bt;
  const int K8 = K >> 3;
  const int iA0 = (bm + r0) * K8 + ch0;
  const int iA1 = (bm + r1) * K8 + ch1;
  const int iB0 = (bn + r0) * K8 + ch0;
  const int iB1 = (bn + r1) * K8 + ch1;
  uint4* lA0 = (uint4*)(smem + s0 * 16);
  uint4* lA1 = (uint4*)(smem + s1 * 16);
  uint4* lB0 = (uint4*)(smem + 8192 + s0 * 16);
  uint4* lB1 = (uint4*)(smem + 8192 + s1 * 16);

  for (int k0 = 0; k0 < K; k0 += 32) {
    const int k8 = k0 >> 3;
    uint4 va0 = gA[iA0 + k8];
    uint4 va1 = gA[iA1 + k8];
    uint4 vb0 = gB[iB0 + k8];
    uint4 vb1 = gB[iB1 + k8];
    __syncthreads();  // prev iter's LDS reads done before overwrite
    *lA0 = va0;
    *lA1 = va1;
    *lB0 = vb0;
    *lB1 = vb1;
    __syncthreads();  // staging visible to all waves
    bf16x8 a[4], b[4];
#pragma unroll
    for (int i = 0; i < 4; ++i)
      a[i] = *(const bf16x8*)(smem + ((quad << 7) + wm + (i << 4) + l16) * 16);
#pragma unroll
    for (int j = 0; j < 4; ++j)
      b[j] = *(const bf16x8*)(smem + 8192 + ((quad << 7) + wn + (j << 4) + l16) * 16);
#pragma unroll
    for (int i = 0; i < 4; ++i)
#pragma unroll
      for (int j = 0; j < 4; ++j)
        acc[i][j] = __builtin_amdgcn_mfma_f32_16x16x32_bf16(a[i], b[j], acc[i][j], 0, 0, 0);
  }

  // epilogue: C/D layout col=lane&15, row=quad*4+reg
#pragma unroll
  for (int j = 0; j < 4; ++j) {
    int col = bn + wn + (j << 4) + l16;
    float bv = bias ? bias[col] : 0.0f;
#pragma unroll
    for (int i = 0; i < 4; ++i) {
      int row0 = bm + wm + (i << 4) + (quad << 2);
#pragma unroll
      for (int r = 0; r < 4; ++r)
        store_out(&C[(row0 + r) * N + col], acc[i][j][r] + bv);
    }
  }
}

extern "C" void kernel_launch(void* const* d_in, const int* in_sizes, int n_in,
                              void* d_out, int out_size, void* d_ws, size_t ws_size,
                              hipStream_t stream) {
  const float* x    = (const float*)d_in[0];
  const float* V    = (const float*)d_in[1];
  const float* U    = (const float*)d_in[2];
  const float* v2   = (const float*)d_in[3];
  const float* v1   = (const float*)d_in[4];
  const float* u2   = (const float*)d_in[5];
  const float* u1   = (const float*)d_in[6];
  const float* V_R  = (const float*)d_in[7];
  const float* U_R  = (const float*)d_in[8];
  const float* v2_R = (const float*)d_in[9];
  const float* v1_R = (const float*)d_in[10];
  const float* u2_R = (const float*)d_in[11];
  const float* u1_R = (const float*)d_in[12];
  const float* bias = (const float*)d_in[13];

  __hip_bfloat16* Xb  = (__hip_bfloat16*)d_ws;          // 8192*4096
  __hip_bfloat16* Wb1 = Xb + 8192 * 4096;               // 2048*4096
  __hip_bfloat16* Wb2 = Wb1 + 2048 * 4096;              // 4096*2048
  __hip_bfloat16* H   = Wb2 + 4096 * 2048;              // 8192*2048
  float* Y = (float*)d_out;

  const int nx = 8192 * 4096;
  convert_x<<<nx / (256 * 8), 256, 0, stream>>>(x, Xb, nx);
  prep_w1<<<4096, 256, 0, stream>>>(V, v2, v1, u2, V_R, v2_R, v1_R, u2_R, Wb1);
  prep_w2<<<4096, 256, 0, stream>>>(U, u1, U_R, u1_R, Wb2);

  // H[8192][2048] = Xb @ Wb1^T
  gemm_bt<__hip_bfloat16><<<dim3(2048 / 128, 8192 / 128), 256, 0, stream>>>(
      Xb, Wb1, H, nullptr, 4096, 2048);
  // Y[8192][4096] = H @ Wb2^T + bias
  gemm_bt<float><<<dim3(4096 / 128, 8192 / 128), 256, 0, stream>>>(
      H, Wb2, Y, bias, 2048, 4096);
}

// Round 4
// 863.232 us; speedup vs baseline: 1.0070x; 1.0070x over previous
//
#include <hip/hip_runtime.h>
#include <hip/hip_bf16.h>
#include <stdint.h>

// LittleBitLinear: y = [(x*v2) @ sign(V)^T * (v1*u2)] @ sign(U)^T * u1  (x2 branches) + bias
// All inputs FLOAT32, output FLOAT32. Fold scales into binarized weights -> two bf16 GEMMs.
//   Xb  [8192][4096]  bf16 copy of x
//   Wb1 [2048][4096]  bf16 (B^T layout), rows 0..1023 branch1, 1024..2047 branch2
//   H   [8192][2048]  bf16 = Xb @ Wb1^T
//   Wb2 [4096][2048]  bf16 (B^T layout), K-concat of both branches, scaled by u1
//   Y   [8192][4096]  fp32 = H @ Wb2^T + bias
//
// Round 4: async global->LDS staging (global_load_lds width=16, m97 structure).
// NOTE: LDS dest pointer must be a real addrspace(3) cast of the shared-mem
// pointer (compiler addrspacecast). Round 1's (uint32_t)(uintptr_t) truncation
// produced garbage LDS offsets -> dropped writes -> NaN.

typedef __bf16 bf16x8 __attribute__((ext_vector_type(8)));
typedef float f32x4 __attribute__((ext_vector_type(4)));

__device__ __forceinline__ void async_copy16(const void* g, void* l) {
  __builtin_amdgcn_global_load_lds(
      (const __attribute__((address_space(1))) uint32_t*)g,
      (__attribute__((address_space(3))) uint32_t*)l,
      16, 0, 0);
}

__device__ __forceinline__ float sgn(float v) {
  return (v > 0.f) ? 1.f : ((v < 0.f) ? -1.f : 0.f);
}

__device__ __forceinline__ void store_out(float* p, float v) { *p = v; }
__device__ __forceinline__ void store_out(__hip_bfloat16* p, float v) { *p = __float2bfloat16(v); }

// fp32 -> bf16, 8 elements/thread, vectorized
__global__ __launch_bounds__(256) void convert_x(const float* __restrict__ x,
                                                 __hip_bfloat16* __restrict__ xb,
                                                 int n) {
  int i = (blockIdx.x * 256 + threadIdx.x) * 8;
  if (i >= n) return;
  const float4* p0 = (const float4*)(x + i);
  float4 a = p0[0], b = p0[1];
  __hip_bfloat16 o[8] = {
      __float2bfloat16(a.x), __float2bfloat16(a.y), __float2bfloat16(a.z), __float2bfloat16(a.w),
      __float2bfloat16(b.x), __float2bfloat16(b.y), __float2bfloat16(b.z), __float2bfloat16(b.w)};
  *(uint4*)(xb + i) = *(const uint4*)o;
}

// Wb1[s][k] = sign(V[s][k]) * v2[k] * v1[s] * u2[s]   (s<1024: branch1, else branch2)
__global__ __launch_bounds__(256) void prep_w1(
    const float* __restrict__ V, const float* __restrict__ v2,
    const float* __restrict__ v1, const float* __restrict__ u2,
    const float* __restrict__ V_R, const float* __restrict__ v2_R,
    const float* __restrict__ v1_R, const float* __restrict__ u2_R,
    __hip_bfloat16* __restrict__ W) {
  int g = blockIdx.x * 256 + threadIdx.x;  // one thread -> 8 consecutive k
  int k = (g & 511) * 8;                   // 4096 / 8 = 512 groups per row
  int s = g >> 9;                          // 0..2047
  const float *Vp, *v2p;
  float rs;
  if (s < 1024) {
    Vp = V + s * 4096 + k; v2p = v2 + k; rs = v1[s] * u2[s];
  } else {
    int ss = s - 1024;
    Vp = V_R + ss * 4096 + k; v2p = v2_R + k; rs = v1_R[ss] * u2_R[ss];
  }
  __hip_bfloat16 o[8];
#pragma unroll
  for (int e = 0; e < 8; ++e)
    o[e] = __float2bfloat16(sgn(Vp[e]) * v2p[e] * rs);
  *(uint4*)(W + s * 4096 + k) = *(const uint4*)o;
}

// Wb2[j][s] = sign(U[j][s]) * u1[j]  (s<1024 branch1, else branch2)
__global__ __launch_bounds__(256) void prep_w2(
    const float* __restrict__ U, const float* __restrict__ u1,
    const float* __restrict__ U_R, const float* __restrict__ u1_R,
    __hip_bfloat16* __restrict__ W) {
  int g = blockIdx.x * 256 + threadIdx.x;  // one thread -> 8 consecutive s
  int s = (g & 255) * 8;                   // 2048 / 8 = 256 groups per row
  int j = g >> 8;                          // 0..4095
  const float* Up;
  float sc;
  if (s < 1024) { Up = U + j * 1024 + s;            sc = u1[j]; }
  else          { Up = U_R + j * 1024 + (s - 1024); sc = u1_R[j]; }
  __hip_bfloat16 o[8];
#pragma unroll
  for (int e = 0; e < 8; ++e)
    o[e] = __float2bfloat16(sgn(Up[e]) * sc);
  *(uint4*)(W + j * 2048 + s) = *(const uint4*)o;
}

// C[M][N] = A[M][K] @ Bt[N][K]^T (+bias), bf16 in, fp32 acc.
// 128x128 block tile, 4 waves (2x2), each wave 64x64 = 4x4 MFMA 16x16x32 tiles.
// BK=32. LDS chunk-major: slot s in [0,512): chunk=s>>7 (k-octet), row=s&127;
// cell=16B (8 bf16). global_load_lds dest = wave base + lane*16 (contiguous slots
// per wave) -> satisfies the wave-uniform-base constraint. ds_read_b128 frags.
template <typename OutT>
__global__ __launch_bounds__(256) void gemm_bt(
    const __hip_bfloat16* __restrict__ A,
    const __hip_bfloat16* __restrict__ Bt,
    OutT* __restrict__ C,
    const float* __restrict__ bias,
    int K, int N) {
  __shared__ char smem[16384];  // A tile [0,8192), B tile [8192,16384)
  const int t = threadIdx.x;
  const int lane = t & 63;
  const int w = t >> 6;
  const int wm = (w >> 1) << 6;   // wave M offset in tile
  const int wn = (w & 1) << 6;    // wave N offset in tile
  const int bm = blockIdx.y << 7;
  const int bn = blockIdx.x << 7;
  const int quad = lane >> 4;
  const int l16 = lane & 15;

  f32x4 acc[4][4] = {};

  // staging: 512 slots per tile, 256 threads -> 2 slots each per tile
  const int s0 = t, s1 = t + 256;
  const int ch0 = s0 >> 7, r0 = s0 & 127;
  const int ch1 = s1 >> 7, r1 = s1 & 127;
  const __hip_bfloat16* gA0 = A + (bm + r0) * K + ch0 * 8;
  const __hip_bfloat16* gA1 = A + (bm + r1) * K + ch1 * 8;
  const __hip_bfloat16* gB0 = Bt + (bn + r0) * K + ch0 * 8;
  const __hip_bfloat16* gB1 = Bt + (bn + r1) * K + ch1 * 8;
  char* lA0 = smem + s0 * 16;
  char* lA1 = smem + s1 * 16;
  char* lB0 = smem + 8192 + s0 * 16;
  char* lB1 = smem + 8192 + s1 * 16;

  for (int k0 = 0; k0 < K; k0 += 32) {
    __syncthreads();  // prev iter's LDS reads done before overwrite
    async_copy16(gA0 + k0, lA0);
    async_copy16(gA1 + k0, lA1);
    async_copy16(gB0 + k0, lB0);
    async_copy16(gB1 + k0, lB1);
    __syncthreads();  // barrier implies vmcnt(0): staging landed
    bf16x8 a[4], b[4];
#pragma unroll
    for (int i = 0; i < 4; ++i)
      a[i] = *(const bf16x8*)(smem + ((quad << 7) + wm + (i << 4) + l16) * 16);
#pragma unroll
    for (int j = 0; j < 4; ++j)
      b[j] = *(const bf16x8*)(smem + 8192 + ((quad << 7) + wn + (j << 4) + l16) * 16);
#pragma unroll
    for (int i = 0; i < 4; ++i)
#pragma unroll
      for (int j = 0; j < 4; ++j)
        acc[i][j] = __builtin_amdgcn_mfma_f32_16x16x32_bf16(a[i], b[j], acc[i][j], 0, 0, 0);
  }

  // epilogue: C/D layout col=lane&15, row=quad*4+reg
#pragma unroll
  for (int j = 0; j < 4; ++j) {
    int col = bn + wn + (j << 4) + l16;
    float bv = bias ? bias[col] : 0.0f;
#pragma unroll
    for (int i = 0; i < 4; ++i) {
      int row0 = bm + wm + (i << 4) + (quad << 2);
#pragma unroll
      for (int r = 0; r < 4; ++r)
        store_out(&C[(row0 + r) * N + col], acc[i][j][r] + bv);
    }
  }
}

extern "C" void kernel_launch(void* const* d_in, const int* in_sizes, int n_in,
                              void* d_out, int out_size, void* d_ws, size_t ws_size,
                              hipStream_t stream) {
  const float* x    = (const float*)d_in[0];
  const float* V    = (const float*)d_in[1];
  const float* U    = (const float*)d_in[2];
  const float* v2   = (const float*)d_in[3];
  const float* v1   = (const float*)d_in[4];
  const float* u2   = (const float*)d_in[5];
  const float* u1   = (const float*)d_in[6];
  const float* V_R  = (const float*)d_in[7];
  const float* U_R  = (const float*)d_in[8];
  const float* v2_R = (const float*)d_in[9];
  const float* v1_R = (const float*)d_in[10];
  const float* u2_R = (const float*)d_in[11];
  const float* u1_R = (const float*)d_in[12];
  const float* bias = (const float*)d_in[13];

  __hip_bfloat16* Xb  = (__hip_bfloat16*)d_ws;          // 8192*4096
  __hip_bfloat16* Wb1 = Xb + 8192 * 4096;               // 2048*4096
  __hip_bfloat16* Wb2 = Wb1 + 2048 * 4096;              // 4096*2048
  __hip_bfloat16* H   = Wb2 + 4096 * 2048;              // 8192*2048
  float* Y = (float*)d_out;

  const int nx = 8192 * 4096;
  convert_x<<<nx / (256 * 8), 256, 0, stream>>>(x, Xb, nx);
  prep_w1<<<4096, 256, 0, stream>>>(V, v2, v1, u2, V_R, v2_R, v1_R, u2_R, Wb1);
  prep_w2<<<4096, 256, 0, stream>>>(U, u1, U_R, u1_R, Wb2);

  // H[8192][2048] = Xb @ Wb1^T
  gemm_bt<__hip_bfloat16><<<dim3(2048 / 128, 8192 / 128), 256, 0, stream>>>(
      Xb, Wb1, H, nullptr, 4096, 2048);
  // Y[8192][4096] = H @ Wb2^T + bias
  gemm_bt<float><<<dim3(4096 / 128, 8192 / 128), 256, 0, stream>>>(
      H, Wb2, Y, bias, 2048, 4096);
}